// Round 2
// baseline (15896.786 us; speedup 1.0000x reference)
//
#include <hip/hip_runtime.h>
#include <stdint.h>
#include <stddef.h>

#define B_ 64
#define T_ 512
#define DIN 256
#define H_ 512
#define G4 2048      // 4*H
#define NWG 32       // recurrence workgroups (512 h-cols / 16 per WG)

typedef __attribute__((ext_vector_type(8))) short short8;
typedef __attribute__((ext_vector_type(4))) float f32x4;

typedef const __attribute__((address_space(1))) unsigned int* gas_ptr;
typedef __attribute__((address_space(3))) unsigned int* las_ptr;

__device__ __forceinline__ unsigned short f2bf(float f) {
  union { float f; unsigned u; } v; v.f = f;
  return (unsigned short)((v.u + 0x7fffu + ((v.u >> 16) & 1u)) >> 16);
}
__device__ __forceinline__ float bf2f(unsigned short s) {
  union { unsigned u; float f; } v; v.u = ((unsigned)s) << 16; return v.f;
}
__device__ __forceinline__ float sigmoidf_(float x) { return 1.f / (1.f + __expf(-x)); }
__device__ __forceinline__ float tanhf_(float x) { return 1.f - 2.f / (__expf(2.f * x) + 1.f); }

__device__ __forceinline__ float ldx(const float* p) { return *p; }
__device__ __forceinline__ float ldx(const unsigned short* p) { return bf2f(*p); }
__device__ __forceinline__ void stc(float* p, float v) { *p = v; }
__device__ __forceinline__ void stc(unsigned short* p, float v) { *p = f2bf(v); }

__device__ __forceinline__ void gload_lds16(const void* g, void* l) {
  __builtin_amdgcn_global_load_lds((gas_ptr)g, (las_ptr)l, 16, 0, 0);
}

// ---------------- converts ----------------
__global__ void k_convert_x(const float* __restrict__ x, unsigned short* __restrict__ xT) {
  const int nq = T_ * B_ * DIN / 4;
  for (int q = blockIdx.x * blockDim.x + threadIdx.x; q < nq; q += gridDim.x * blockDim.x) {
    int e = q * 4;
    int d = e % DIN;
    int row = e / DIN;            // t*B + b
    int b = row & (B_ - 1), t = row / B_;
    float4 v = *(const float4*)(x + ((size_t)b * T_ + t) * DIN + d);
    unsigned short o[4] = { f2bf(v.x), f2bf(v.y), f2bf(v.z), f2bf(v.w) };
    *(uint2*)(xT + (size_t)row * DIN + d) = *(const uint2*)o;
  }
}

__global__ void k_convert_w(const float* __restrict__ w, unsigned short* __restrict__ o, int n) {
  const int nq = n / 4;
  for (int q = blockIdx.x * blockDim.x + threadIdx.x; q < nq; q += gridDim.x * blockDim.x) {
    float4 v = *(const float4*)(w + q * 4);
    unsigned short s[4] = { f2bf(v.x), f2bf(v.y), f2bf(v.z), f2bf(v.w) };
    *(uint2*)(o + q * 4) = *(const uint2*)s;
  }
}

// ---------------- GEMM: C[M,2048] = A[M,K](bf16) @ W[2048,K]^T(bf16) + (ba+bb) ----------------
template <typename XGT>
__global__ __launch_bounds__(256, 1) void k_gemm_bias(
    const unsigned short* __restrict__ A, const unsigned short* __restrict__ Bw,
    const float* __restrict__ ba, const float* __restrict__ bb,
    XGT* __restrict__ C, int K, int ntn) {
  __shared__ unsigned short lds[16384];
  const int bid = blockIdx.x;
  const int nt = bid % ntn, mt = bid / ntn;
  const int tid = threadIdx.x;
  const int lane = tid & 63, wv = tid >> 6;
  const int wm = wv & 1, wn = wv >> 1;
  f32x4 acc[4][4] = {};
  const int nkt = K >> 6;
  const size_t ar0 = (size_t)mt * 128, br0 = (size_t)nt * 128;
  for (int kt = 0; kt < nkt; ++kt) {
    __syncthreads();
#pragma unroll
    for (int jj = 0; jj < 4; ++jj) {
      int g = tid + jj * 256;
      int row = g >> 3, gc = g & 7;
      int dst = (((row >> 4) * 2 + (gc >> 2)) * 64 + ((row & 15) + ((gc & 3) << 4))) * 8;
      uint4 va = *(const uint4*)(A + (ar0 + row) * (size_t)K + (size_t)kt * 64 + gc * 8);
      *(uint4*)&lds[dst] = va;
      uint4 vb = *(const uint4*)(Bw + (br0 + row) * (size_t)K + (size_t)kt * 64 + gc * 8);
      *(uint4*)&lds[8192 + dst] = vb;
    }
    __syncthreads();
#pragma unroll
    for (int kk = 0; kk < 2; ++kk) {
      short8 af[4], bf[4];
#pragma unroll
      for (int m = 0; m < 4; ++m)
        af[m] = *(const short8*)&lds[(((wm * 4 + m) * 2 + kk) * 64 + lane) * 8];
#pragma unroll
      for (int n = 0; n < 4; ++n)
        bf[n] = *(const short8*)&lds[8192 + (((wn * 4 + n) * 2 + kk) * 64 + lane) * 8];
#pragma unroll
      for (int m = 0; m < 4; ++m)
#pragma unroll
        for (int n = 0; n < 4; ++n)
          acc[m][n] = __builtin_amdgcn_mfma_f32_16x16x32_bf16(af[m], bf[n], acc[m][n], 0, 0, 0);
    }
  }
#pragma unroll
  for (int n = 0; n < 4; ++n) {
    int col = (int)br0 + wn * 64 + n * 16 + (lane & 15);
    float bsum = ba[col] + bb[col];
#pragma unroll
    for (int m = 0; m < 4; ++m) {
      size_t row = ar0 + wm * 64 + m * 16 + ((lane >> 4) * 4);
#pragma unroll
      for (int r = 0; r < 4; ++r)
        stc(C + (row + r) * G4 + col, acc[m][n][r] + bsum);
    }
  }
}

// ---------------- persistent LSTM recurrence (v2) ----------------
// 32 WGs x 2 waves. WG wg owns h-cols [wg*16, wg*16+16) for ALL 64 batches.
// Wave w computes gate sections s = {2w, 2w+1} for all 4 m-tiles; weights live in
// 128 VGPRs per wave. h(t-1) is staged into LDS via global_load_lds (frag-packed,
// all 64 loads in flight at once). Gates exchanged via padded LDS. Per-WG monotone
// flag barrier: relaxed store/poll on private 128B lines + threadfence both sides.
template <typename XGT>
__global__ __launch_bounds__(128, 1) void k_lstm2(
    const XGT* __restrict__ xg,          // [T,B,4H]
    const float* __restrict__ w_hh,      // [4H,H] fp32
    unsigned short* __restrict__ h_out,  // [T,B,H] bf16
    int* __restrict__ flags) {           // NWG flags, stride 32 ints (128B)
  __shared__ unsigned short hbuf[B_ * H_];   // 64KB, frag-packed: frag f=(kk*4+m), 1KB each
  __shared__ float gx[2][64][17];            // padded gate-exchange buffer
  const int wg = blockIdx.x;
  const int tid = threadIdx.x;
  const int lane = tid & 63, wv = tid >> 6;
  const int l15 = lane & 15, l4 = lane >> 4;
  const int mbase = wv * 2;

  // ---- weights -> VGPR: wreg[sl][kk], B-frag for gate section s = 2*wv+sl ----
  short8 wreg[2][16];
#pragma unroll
  for (int sl = 0; sl < 2; ++sl) {
    const int s = wv * 2 + sl;
    const float* wrow = w_hh + (size_t)(s * H_ + wg * 16 + l15) * H_ + l4 * 8;
#pragma unroll
    for (int kk = 0; kk < 16; ++kk) {
      float4 v0 = *(const float4*)(wrow + kk * 32);
      float4 v1 = *(const float4*)(wrow + kk * 32 + 4);
      unsigned short o[8] = { f2bf(v0.x), f2bf(v0.y), f2bf(v0.z), f2bf(v0.w),
                              f2bf(v1.x), f2bf(v1.y), f2bf(v1.z), f2bf(v1.w) };
      wreg[sl][kk] = *(const short8*)o;
    }
  }

  float c[2][4] = {};   // cell state for my m's (m = mbase+ml), rows l4*4+r

  for (int t = 0; t < T_; ++t) {
    // ---- wait for h(t-1), then stage it into LDS ----
    if (t > 0) {
      int v;
      for (;;) {
        v = (lane < NWG)
              ? __hip_atomic_load(flags + lane * 32, __ATOMIC_RELAXED, __HIP_MEMORY_SCOPE_AGENT)
              : 0x7fffffff;
        if (__all(v >= t)) break;
        __builtin_amdgcn_s_sleep(1);
      }
      __threadfence();  // acquire side: order subsequent h loads after flag observation
      const unsigned short* hl = h_out + (size_t)(t - 1) * (B_ * H_) + (size_t)l15 * H_ + l4 * 8;
#pragma unroll
      for (int fi = 0; fi < 32; ++fi) {
        const int f = wv * 32 + fi;
        const int kk = f >> 2, m = f & 3;
        gload_lds16(hl + (size_t)(m * 16) * H_ + kk * 32, &hbuf[f * 512]);
      }
    }

    // ---- xg prefetch for THIS tick (overlaps stage latency) ----
    float xr[2][4][4];
    {
      const XGT* xb = xg + (size_t)t * (B_ * G4) + (size_t)(mbase * 16 + l4 * 4) * G4 + wg * 16 + l15;
#pragma unroll
      for (int ml = 0; ml < 2; ++ml)
#pragma unroll
        for (int r = 0; r < 4; ++r)
#pragma unroll
          for (int s = 0; s < 4; ++s)
            xr[ml][r][s] = ldx(xb + (size_t)(ml * 16 + r) * G4 + s * H_);
    }

    // ---- hidden matmul: acc[m][sl] over K=512 ----
    f32x4 acc[4][2] = {};
    if (t > 0) {
      __syncthreads();  // drains vmcnt -> hbuf staged by both waves
#pragma unroll
      for (int kk = 0; kk < 16; ++kk) {
        short8 a[4];
#pragma unroll
        for (int m = 0; m < 4; ++m)
          a[m] = *(const short8*)&hbuf[(kk * 4 + m) * 512 + lane * 8];
#pragma unroll
        for (int m = 0; m < 4; ++m)
#pragma unroll
          for (int sl = 0; sl < 2; ++sl)
            acc[m][sl] = __builtin_amdgcn_mfma_f32_16x16x32_bf16(a[m], wreg[sl][kk], acc[m][sl], 0, 0, 0);
      }
    }

    // ---- exchange the other wave's m-pair gates ----
    {
      const int mo = (1 - wv) * 2;
#pragma unroll
      for (int ml = 0; ml < 2; ++ml)
#pragma unroll
        for (int sl = 0; sl < 2; ++sl)
#pragma unroll
          for (int r = 0; r < 4; ++r)
            gx[wv][lane][ml * 8 + sl * 4 + r] = acc[mo + ml][sl][r];
    }
    __syncthreads();
    float og[2][2][4];  // other wave's sections for MY m's
#pragma unroll
    for (int ml = 0; ml < 2; ++ml)
#pragma unroll
      for (int sl = 0; sl < 2; ++sl)
#pragma unroll
        for (int r = 0; r < 4; ++r)
          og[ml][sl][r] = gx[1 - wv][lane][ml * 8 + sl * 4 + r];

    // ---- cell update + h store (wave w handles m = 2w, 2w+1) ----
    unsigned short* hw = h_out + (size_t)t * (B_ * H_) + wg * 16 + l15;
#pragma unroll
    for (int ml = 0; ml < 2; ++ml)
#pragma unroll
      for (int r = 0; r < 4; ++r) {
        const int m = mbase + ml;
        float s0 = acc[m][0][r], s1 = acc[m][1][r];
        float o0 = og[ml][0][r], o1 = og[ml][1][r];
        float gi, gf, gg, go;
        if (wv == 0) { gi = s0; gf = s1; gg = o0; go = o1; }
        else         { gi = o0; gf = o1; gg = s0; go = s1; }
        gi += xr[ml][r][0]; gf += xr[ml][r][1]; gg += xr[ml][r][2]; go += xr[ml][r][3];
        float iv = sigmoidf_(gi);
        float fv = sigmoidf_(gf);
        float gv = tanhf_(gg);
        float ov = sigmoidf_(go);
        float cn = fv * c[ml][r] + iv * gv;
        c[ml][r] = cn;
        hw[(size_t)(m * 16 + l4 * 4 + r) * H_] = f2bf(ov * tanhf_(cn));
      }

    // ---- publish h(t) ----
    if (t + 1 < T_) {
      __threadfence();   // release: drain h stores to coherent point
      __syncthreads();   // both waves' fences done
      if (tid == 0)
        __hip_atomic_store(flags + wg * 32, t + 1, __ATOMIC_RELAXED, __HIP_MEMORY_SCOPE_AGENT);
    }
  }
}

// ---------------- final FC + sigmoid ----------------
__global__ void k_fc(const unsigned short* __restrict__ h, const float* __restrict__ w,
                     const float* __restrict__ bfc, float* __restrict__ out) {
  int b = threadIdx.x;
  if (b < B_) {
    const unsigned short* hb = h + (size_t)b * H_;
    float s = 0.f;
    for (int j = 0; j < H_; ++j) s += bf2f(hb[j]) * w[j];
    out[b] = sigmoidf_(s + bfc[0]);
  }
}

extern "C" void kernel_launch(void* const* d_in, const int* in_sizes, int n_in,
                              void* d_out, int out_size, void* d_ws, size_t ws_size,
                              hipStream_t stream) {
  (void)in_sizes; (void)n_in; (void)out_size;
  const float* x    = (const float*)d_in[0];
  const float* wih0 = (const float*)d_in[1];
  const float* whh0 = (const float*)d_in[2];
  const float* bih0 = (const float*)d_in[3];
  const float* bhh0 = (const float*)d_in[4];
  const float* wih1 = (const float*)d_in[5];
  const float* whh1 = (const float*)d_in[6];
  const float* bih1 = (const float*)d_in[7];
  const float* bhh1 = (const float*)d_in[8];
  const float* wfc  = (const float*)d_in[9];
  const float* bfc  = (const float*)d_in[10];
  float* out = (float*)d_out;

  char* ws = (char*)d_ws;
  int* flags = (int*)ws;                    // [0, 8192): 2 layers x 32 flags x 128B
  size_t off = 8192;
  unsigned short* xT = (unsigned short*)(ws + off);    off += (size_t)T_ * B_ * DIN * 2;
  unsigned short* wih0b = (unsigned short*)(ws + off); off += (size_t)G4 * DIN * 2;
  unsigned short* wih1b = (unsigned short*)(ws + off); off += (size_t)G4 * H_ * 2;
  unsigned short* h0 = (unsigned short*)(ws + off);    off += (size_t)T_ * B_ * H_ * 2;
  unsigned short* h1 = (unsigned short*)(ws + off);    off += (size_t)T_ * B_ * H_ * 2;
  size_t xg_off = off;
  const size_t need_f32 = xg_off + (size_t)T_ * B_ * G4 * 4;

  const int gemm_grid = (T_ * B_ / 128) * (G4 / 128);
  const int ntn = G4 / 128;

  hipMemsetAsync(flags, 0, 8192, stream);
  k_convert_x<<<2048, 256, 0, stream>>>(x, xT);
  k_convert_w<<<512, 256, 0, stream>>>(wih0, wih0b, G4 * DIN);
  k_convert_w<<<1024, 256, 0, stream>>>(wih1, wih1b, G4 * H_);

  if (ws_size >= need_f32) {
    float* xgbuf = (float*)(ws + xg_off);
    k_gemm_bias<float><<<gemm_grid, 256, 0, stream>>>(xT, wih0b, bih0, bhh0, xgbuf, DIN, ntn);
    k_lstm2<float><<<NWG, 128, 0, stream>>>(xgbuf, whh0, h0, flags);
    k_gemm_bias<float><<<gemm_grid, 256, 0, stream>>>(h0, wih1b, bih1, bhh1, xgbuf, H_, ntn);
    k_lstm2<float><<<NWG, 128, 0, stream>>>(xgbuf, whh1, h1, flags + 1024);
  } else {
    unsigned short* xgbuf = (unsigned short*)(ws + xg_off);
    k_gemm_bias<unsigned short><<<gemm_grid, 256, 0, stream>>>(xT, wih0b, bih0, bhh0, xgbuf, DIN, ntn);
    k_lstm2<unsigned short><<<NWG, 128, 0, stream>>>(xgbuf, whh0, h0, flags);
    k_gemm_bias<unsigned short><<<gemm_grid, 256, 0, stream>>>(h0, wih1b, bih1, bhh1, xgbuf, H_, ntn);
    k_lstm2<unsigned short><<<NWG, 128, 0, stream>>>(xgbuf, whh1, h1, flags + 1024);
  }
  k_fc<<<1, 64, 0, stream>>>(h1 + (size_t)(T_ - 1) * B_ * H_, wfc, bfc, out);
}

// Round 3
// 3352.844 us; speedup vs baseline: 4.7413x; 4.7413x over previous
//
#include <hip/hip_runtime.h>
#include <stdint.h>
#include <stddef.h>

#define B_ 64
#define T_ 512
#define DIN 256
#define H_ 512
#define G4 2048      // 4*H
#define NWG2 64      // recurrence WGs: 32 col-groups x 2 batch-halves

typedef __attribute__((ext_vector_type(8))) short short8;
typedef __attribute__((ext_vector_type(4))) float f32x4;

__device__ __forceinline__ unsigned short f2bf(float f) {
  union { float f; unsigned u; } v; v.f = f;
  return (unsigned short)((v.u + 0x7fffu + ((v.u >> 16) & 1u)) >> 16);
}
__device__ __forceinline__ float bf2f(unsigned short s) {
  union { unsigned u; float f; } v; v.u = ((unsigned)s) << 16; return v.f;
}
__device__ __forceinline__ float sigmoidf_(float x) { return 1.f / (1.f + __expf(-x)); }
__device__ __forceinline__ float tanhf_(float x) { return 1.f - 2.f / (__expf(2.f * x) + 1.f); }

__device__ __forceinline__ float ldx(const float* p) { return *p; }
__device__ __forceinline__ float ldx(const unsigned short* p) { return bf2f(*p); }
__device__ __forceinline__ void stc(float* p, float v) { *p = v; }
__device__ __forceinline__ void stc(unsigned short* p, float v) { *p = f2bf(v); }

// coherent (LLC, sc0|sc1) accesses -- no cache-maintenance side effects
__device__ __forceinline__ unsigned long long cohload_u64(const void* p) {
  return __hip_atomic_load((const unsigned long long*)p, __ATOMIC_RELAXED, __HIP_MEMORY_SCOPE_AGENT);
}
__device__ __forceinline__ void cohstore_u64(void* p, unsigned long long v) {
  __hip_atomic_store((unsigned long long*)p, v, __ATOMIC_RELAXED, __HIP_MEMORY_SCOPE_AGENT);
}
__device__ __forceinline__ int cohload_i32(const int* p) {
  return __hip_atomic_load(p, __ATOMIC_RELAXED, __HIP_MEMORY_SCOPE_AGENT);
}
__device__ __forceinline__ void cohstore_i32(int* p, int v) {
  __hip_atomic_store(p, v, __ATOMIC_RELAXED, __HIP_MEMORY_SCOPE_AGENT);
}

// ---------------- converts ----------------
__global__ void k_convert_x(const float* __restrict__ x, unsigned short* __restrict__ xT) {
  const int nq = T_ * B_ * DIN / 4;
  for (int q = blockIdx.x * blockDim.x + threadIdx.x; q < nq; q += gridDim.x * blockDim.x) {
    int e = q * 4;
    int d = e % DIN;
    int row = e / DIN;            // t*B + b
    int b = row & (B_ - 1), t = row / B_;
    float4 v = *(const float4*)(x + ((size_t)b * T_ + t) * DIN + d);
    unsigned short o[4] = { f2bf(v.x), f2bf(v.y), f2bf(v.z), f2bf(v.w) };
    *(uint2*)(xT + (size_t)row * DIN + d) = *(const uint2*)o;
  }
}

__global__ void k_convert_w(const float* __restrict__ w, unsigned short* __restrict__ o, int n) {
  const int nq = n / 4;
  for (int q = blockIdx.x * blockDim.x + threadIdx.x; q < nq; q += gridDim.x * blockDim.x) {
    float4 v = *(const float4*)(w + q * 4);
    unsigned short s[4] = { f2bf(v.x), f2bf(v.y), f2bf(v.z), f2bf(v.w) };
    *(uint2*)(o + q * 4) = *(const uint2*)s;
  }
}

// ---------------- GEMM: C[M,2048] = A[M,K](bf16) @ W[2048,K]^T(bf16) + (ba+bb) ----------------
template <typename XGT>
__global__ __launch_bounds__(256, 1) void k_gemm_bias(
    const unsigned short* __restrict__ A, const unsigned short* __restrict__ Bw,
    const float* __restrict__ ba, const float* __restrict__ bb,
    XGT* __restrict__ C, int K, int ntn) {
  __shared__ unsigned short lds[16384];
  const int bid = blockIdx.x;
  const int nt = bid % ntn, mt = bid / ntn;
  const int tid = threadIdx.x;
  const int lane = tid & 63, wv = tid >> 6;
  const int wm = wv & 1, wn = wv >> 1;
  f32x4 acc[4][4] = {};
  const int nkt = K >> 6;
  const size_t ar0 = (size_t)mt * 128, br0 = (size_t)nt * 128;
  for (int kt = 0; kt < nkt; ++kt) {
    __syncthreads();
#pragma unroll
    for (int jj = 0; jj < 4; ++jj) {
      int g = tid + jj * 256;
      int row = g >> 3, gc = g & 7;
      int dst = (((row >> 4) * 2 + (gc >> 2)) * 64 + ((row & 15) + ((gc & 3) << 4))) * 8;
      uint4 va = *(const uint4*)(A + (ar0 + row) * (size_t)K + (size_t)kt * 64 + gc * 8);
      *(uint4*)&lds[dst] = va;
      uint4 vb = *(const uint4*)(Bw + (br0 + row) * (size_t)K + (size_t)kt * 64 + gc * 8);
      *(uint4*)&lds[8192 + dst] = vb;
    }
    __syncthreads();
#pragma unroll
    for (int kk = 0; kk < 2; ++kk) {
      short8 af[4], bf[4];
#pragma unroll
      for (int m = 0; m < 4; ++m)
        af[m] = *(const short8*)&lds[(((wm * 4 + m) * 2 + kk) * 64 + lane) * 8];
#pragma unroll
      for (int n = 0; n < 4; ++n)
        bf[n] = *(const short8*)&lds[8192 + (((wn * 4 + n) * 2 + kk) * 64 + lane) * 8];
#pragma unroll
      for (int m = 0; m < 4; ++m)
#pragma unroll
        for (int n = 0; n < 4; ++n)
          acc[m][n] = __builtin_amdgcn_mfma_f32_16x16x32_bf16(af[m], bf[n], acc[m][n], 0, 0, 0);
    }
  }
#pragma unroll
  for (int n = 0; n < 4; ++n) {
    int col = (int)br0 + wn * 64 + n * 16 + (lane & 15);
    float bsum = ba[col] + bb[col];
#pragma unroll
    for (int m = 0; m < 4; ++m) {
      size_t row = ar0 + wm * 64 + m * 16 + ((lane >> 4) * 4);
#pragma unroll
      for (int r = 0; r < 4; ++r)
        stc(C + (row + r) * G4 + col, acc[m][n][r] + bsum);
    }
  }
}

// ---------------- persistent LSTM recurrence (v3: fence-free LLC protocol) ----------------
// 64 WGs x 4 waves. WG (cg,bh): h-cols [cg*16,+16), batches [bh*32,+32).
// Wave s computes gate section s (i,f,g,o) for its 2 batch m-tiles; W_hh frags in VGPRs.
// h exchanged via LLC: relaxed agent atomics (sc0|sc1) only -- NO fences (no buffer_wbl2/inv).
// Producer: coherent h stores -> vmcnt(0) -> barrier -> coherent flag store.
// Consumer: poll flag -> sched_barrier -> coherent h loads -> LDS (XOR-swizzled) -> MFMA.
template <typename XGT>
__global__ __launch_bounds__(256, 1) void k_lstm3(
    const XGT* __restrict__ xg,          // [T,B,4H]
    const float* __restrict__ w_hh,      // [4H,H] fp32
    unsigned short* __restrict__ h_out,  // [T,B,H] bf16
    int* __restrict__ flags) {           // NWG2 flags, stride 32 ints (128B)
  __shared__ unsigned short hbuf[32 * 512];   // 32KB: rows=local batch, XOR-swizzled 16B granules
  __shared__ float gbuf[8 * 64 * 5];          // 10KB: gate exchange, stride-5 padded
  __shared__ unsigned short hstage[32 * 16];  // 1KB: h(t) block before store
  const int wgid = blockIdx.x;
  const int cg = wgid >> 1, bh = wgid & 1;
  const int tid = threadIdx.x;
  const int lane = tid & 63, wv = tid >> 6;
  const int l15 = lane & 15, l4 = lane >> 4;

  // ---- weights -> VGPR: wave wv holds B-frags for gate section wv ----
  short8 wreg[16];
  {
    const float* wrow = w_hh + ((size_t)wv * H_ + cg * 16 + l15) * H_ + l4 * 8;
#pragma unroll
    for (int kk = 0; kk < 16; ++kk) {
      float4 v0 = *(const float4*)(wrow + kk * 32);
      float4 v1 = *(const float4*)(wrow + kk * 32 + 4);
      unsigned short o[8] = { f2bf(v0.x), f2bf(v0.y), f2bf(v0.z), f2bf(v0.w),
                              f2bf(v1.x), f2bf(v1.y), f2bf(v1.z), f2bf(v1.w) };
      wreg[kk] = *(const short8*)o;
    }
  }

  // update-phase role: wave handles m=um, rows r in {rb, rb+1}
  const int um = wv >> 1, rb = (wv & 1) * 2;
  float c2[2] = {0.f, 0.f};

  for (int t = 0; t < T_; ++t) {
    // ---- xg prefetch for this tick's update cells (plain cached loads) ----
    float xr[2][4];
    {
      const XGT* xb = xg + ((size_t)t * B_ + bh * 32 + um * 16 + l4 * 4 + rb) * (size_t)G4 + cg * 16 + l15;
#pragma unroll
      for (int rr = 0; rr < 2; ++rr)
#pragma unroll
        for (int s = 0; s < 4; ++s)
          xr[rr][s] = ldx(xb + (size_t)rr * G4 + s * H_);
    }

    f32x4 acc[2] = {};
    if (t > 0) {
      // ---- wait for the 32 producers of my batch-half ----
      const int fl = ((lane & 31) * 2 + bh) * 32;
      for (;;) {
        int v = (lane < 32) ? cohload_i32(flags + fl) : 0x7fffffff;
        if (__all(v >= t)) break;
        __builtin_amdgcn_s_sleep(1);
      }
      __builtin_amdgcn_sched_barrier(0);
      asm volatile("" ::: "memory");
      // ---- stage h(t-1)[bh half] -> LDS, 8x16B chunks per thread, coherent loads ----
      const char* hp = (const char*)(h_out + ((size_t)(t - 1) * B_ + bh * 32) * H_);
      unsigned long long tmp[16];
#pragma unroll
      for (int j = 0; j < 8; ++j) {
        int ch = tid + j * 256;           // 16B chunk id, 0..2047
        tmp[2 * j]     = cohload_u64(hp + (size_t)ch * 16);
        tmp[2 * j + 1] = cohload_u64(hp + (size_t)ch * 16 + 8);
      }
#pragma unroll
      for (int j = 0; j < 8; ++j) {
        int ch = tid + j * 256;
        int b = ch >> 6, ke = (ch & 63) * 8;                 // row, elem col
        int dst = b * 512 + (ke ^ ((b & 7) << 3));           // XOR-swizzled
        union { unsigned long long q[2]; uint4 v; } u;
        u.q[0] = tmp[2 * j]; u.q[1] = tmp[2 * j + 1];
        *(uint4*)&hbuf[dst] = u.v;
      }
    }
    __syncthreads();

    // ---- hidden matmul: acc[m] += h(t-1) @ W_hh[sec wv] over K=512 ----
    if (t > 0) {
#pragma unroll
      for (int kk = 0; kk < 16; ++kk) {
        int ke = kk * 32 + l4 * 8;
        short8 a0 = *(const short8*)&hbuf[(0 * 16 + l15) * 512 + (ke ^ ((l15 & 7) << 3))];
        short8 a1 = *(const short8*)&hbuf[(1 * 16 + l15) * 512 + (ke ^ ((l15 & 7) << 3))];
        acc[0] = __builtin_amdgcn_mfma_f32_16x16x32_bf16(a0, wreg[kk], acc[0], 0, 0, 0);
        acc[1] = __builtin_amdgcn_mfma_f32_16x16x32_bf16(a1, wreg[kk], acc[1], 0, 0, 0);
      }
    }

    // ---- gate exchange: wave wv(section) publishes acc for both m-tiles ----
#pragma unroll
    for (int m = 0; m < 2; ++m)
#pragma unroll
      for (int r = 0; r < 4; ++r)
        gbuf[((wv * 2 + m) * 64 + lane) * 5 + r] = acc[m][r];
    __syncthreads();

    // ---- cell update (wave role: m=um, r in {rb,rb+1}) ----
#pragma unroll
    for (int rr = 0; rr < 2; ++rr) {
      int r = rb + rr;
      float g4v[4];
#pragma unroll
      for (int s = 0; s < 4; ++s)
        g4v[s] = gbuf[((s * 2 + um) * 64 + lane) * 5 + r] + xr[rr][s];
      float iv = sigmoidf_(g4v[0]);
      float fv = sigmoidf_(g4v[1]);
      float gv = tanhf_(g4v[2]);
      float ov = sigmoidf_(g4v[3]);
      float cn = fv * c2[rr] + iv * gv;
      c2[rr] = cn;
      hstage[(um * 16 + l4 * 4 + r) * 16 + l15] = f2bf(ov * tanhf_(cn));
    }
    __syncthreads();

    // ---- publish h(t): coherent 8B stores -> vmcnt(0) -> barrier -> flag ----
    if (tid < 128) {
      int bl = tid >> 2, q = tid & 3;
      unsigned long long v = *(const unsigned long long*)&hstage[bl * 16 + q * 4];
      cohstore_u64(h_out + ((size_t)t * B_ + bh * 32 + bl) * H_ + cg * 16 + q * 4, v);
    }
    asm volatile("s_waitcnt vmcnt(0)" ::: "memory");
    __syncthreads();
    if (tid == 0) cohstore_i32(flags + wgid * 32, t + 1);
    __syncthreads();
  }
}

// ---------------- final FC + sigmoid ----------------
__global__ void k_fc(const unsigned short* __restrict__ h, const float* __restrict__ w,
                     const float* __restrict__ bfc, float* __restrict__ out) {
  int b = threadIdx.x;
  if (b < B_) {
    const unsigned short* hb = h + (size_t)b * H_;
    float s = 0.f;
    for (int j = 0; j < H_; ++j) s += bf2f(hb[j]) * w[j];
    out[b] = sigmoidf_(s + bfc[0]);
  }
}

extern "C" void kernel_launch(void* const* d_in, const int* in_sizes, int n_in,
                              void* d_out, int out_size, void* d_ws, size_t ws_size,
                              hipStream_t stream) {
  (void)in_sizes; (void)n_in; (void)out_size;
  const float* x    = (const float*)d_in[0];
  const float* wih0 = (const float*)d_in[1];
  const float* whh0 = (const float*)d_in[2];
  const float* bih0 = (const float*)d_in[3];
  const float* bhh0 = (const float*)d_in[4];
  const float* wih1 = (const float*)d_in[5];
  const float* whh1 = (const float*)d_in[6];
  const float* bih1 = (const float*)d_in[7];
  const float* bhh1 = (const float*)d_in[8];
  const float* wfc  = (const float*)d_in[9];
  const float* bfc  = (const float*)d_in[10];
  float* out = (float*)d_out;

  char* ws = (char*)d_ws;
  int* flags = (int*)ws;                    // [0, 16384): 2 layers x 64 flags x 128B
  size_t off = 16384;
  unsigned short* xT = (unsigned short*)(ws + off);    off += (size_t)T_ * B_ * DIN * 2;
  unsigned short* wih0b = (unsigned short*)(ws + off); off += (size_t)G4 * DIN * 2;
  unsigned short* wih1b = (unsigned short*)(ws + off); off += (size_t)G4 * H_ * 2;
  unsigned short* h0 = (unsigned short*)(ws + off);    off += (size_t)T_ * B_ * H_ * 2;
  unsigned short* h1 = (unsigned short*)(ws + off);    off += (size_t)T_ * B_ * H_ * 2;
  size_t xg_off = off;
  const size_t need_f32 = xg_off + (size_t)T_ * B_ * G4 * 4;

  const int gemm_grid = (T_ * B_ / 128) * (G4 / 128);
  const int ntn = G4 / 128;

  hipMemsetAsync(flags, 0, 16384, stream);
  k_convert_x<<<2048, 256, 0, stream>>>(x, xT);
  k_convert_w<<<512, 256, 0, stream>>>(wih0, wih0b, G4 * DIN);
  k_convert_w<<<1024, 256, 0, stream>>>(wih1, wih1b, G4 * H_);

  if (ws_size >= need_f32) {
    float* xgbuf = (float*)(ws + xg_off);
    k_gemm_bias<float><<<gemm_grid, 256, 0, stream>>>(xT, wih0b, bih0, bhh0, xgbuf, DIN, ntn);
    k_lstm3<float><<<NWG2, 256, 0, stream>>>(xgbuf, whh0, h0, flags);
    k_gemm_bias<float><<<gemm_grid, 256, 0, stream>>>(h0, wih1b, bih1, bhh1, xgbuf, H_, ntn);
    k_lstm3<float><<<NWG2, 256, 0, stream>>>(xgbuf, whh1, h1, flags + 2048);
  } else {
    unsigned short* xgbuf = (unsigned short*)(ws + xg_off);
    k_gemm_bias<unsigned short><<<gemm_grid, 256, 0, stream>>>(xT, wih0b, bih0, bhh0, xgbuf, DIN, ntn);
    k_lstm3<unsigned short><<<NWG2, 256, 0, stream>>>(xgbuf, whh0, h0, flags);
    k_gemm_bias<unsigned short><<<gemm_grid, 256, 0, stream>>>(h0, wih1b, bih1, bhh1, xgbuf, H_, ntn);
    k_lstm3<unsigned short><<<NWG2, 256, 0, stream>>>(xgbuf, whh1, h1, flags + 2048);
  }
  k_fc<<<1, 64, 0, stream>>>(h1 + (size_t)(T_ - 1) * B_ * H_, wfc, bfc, out);
}

// Round 4
// 2346.826 us; speedup vs baseline: 6.7737x; 1.4287x over previous
//
#include <hip/hip_runtime.h>
#include <stdint.h>
#include <stddef.h>

#define B_ 64
#define T_ 512
#define DIN 256
#define H_ 512
#define G4 2048      // 4*H
#define NWGF 128     // fused: 64 layer-0 WGs + 64 layer-1 WGs

typedef __attribute__((ext_vector_type(8))) short short8;
typedef __attribute__((ext_vector_type(4))) float f32x4;

__device__ __forceinline__ unsigned short f2bf(float f) {
  union { float f; unsigned u; } v; v.f = f;
  return (unsigned short)((v.u + 0x7fffu + ((v.u >> 16) & 1u)) >> 16);
}
__device__ __forceinline__ float bf2f(unsigned short s) {
  union { unsigned u; float f; } v; v.u = ((unsigned)s) << 16; return v.f;
}
__device__ __forceinline__ float sigmoidf_(float x) { return 1.f / (1.f + __expf(-x)); }
__device__ __forceinline__ float tanhf_(float x) { return 1.f - 2.f / (__expf(2.f * x) + 1.f); }

__device__ __forceinline__ float ldx(const float* p) { return *p; }
__device__ __forceinline__ float ldx(const unsigned short* p) { return bf2f(*p); }
__device__ __forceinline__ void stc(float* p, float v) { *p = v; }
__device__ __forceinline__ void stc(unsigned short* p, float v) { *p = f2bf(v); }

// coherent (LLC, sc0|sc1) accesses -- no cache-maintenance side effects
__device__ __forceinline__ unsigned long long cohload_u64(const void* p) {
  return __hip_atomic_load((const unsigned long long*)p, __ATOMIC_RELAXED, __HIP_MEMORY_SCOPE_AGENT);
}
__device__ __forceinline__ void cohstore_u64(void* p, unsigned long long v) {
  __hip_atomic_store((unsigned long long*)p, v, __ATOMIC_RELAXED, __HIP_MEMORY_SCOPE_AGENT);
}
__device__ __forceinline__ int cohload_i32(const int* p) {
  return __hip_atomic_load(p, __ATOMIC_RELAXED, __HIP_MEMORY_SCOPE_AGENT);
}
__device__ __forceinline__ void cohstore_i32(int* p, int v) {
  __hip_atomic_store(p, v, __ATOMIC_RELAXED, __HIP_MEMORY_SCOPE_AGENT);
}

// ---------------- converts ----------------
__global__ void k_convert_x(const float* __restrict__ x, unsigned short* __restrict__ xT) {
  const int nq = T_ * B_ * DIN / 4;
  for (int q = blockIdx.x * blockDim.x + threadIdx.x; q < nq; q += gridDim.x * blockDim.x) {
    int e = q * 4;
    int d = e % DIN;
    int row = e / DIN;            // t*B + b
    int b = row & (B_ - 1), t = row / B_;
    float4 v = *(const float4*)(x + ((size_t)b * T_ + t) * DIN + d);
    unsigned short o[4] = { f2bf(v.x), f2bf(v.y), f2bf(v.z), f2bf(v.w) };
    *(uint2*)(xT + (size_t)row * DIN + d) = *(const uint2*)o;
  }
}

__global__ void k_convert_w(const float* __restrict__ w, unsigned short* __restrict__ o, int n) {
  const int nq = n / 4;
  for (int q = blockIdx.x * blockDim.x + threadIdx.x; q < nq; q += gridDim.x * blockDim.x) {
    float4 v = *(const float4*)(w + q * 4);
    unsigned short s[4] = { f2bf(v.x), f2bf(v.y), f2bf(v.z), f2bf(v.w) };
    *(uint2*)(o + q * 4) = *(const uint2*)s;
  }
}

// ---------------- GEMM: C[M,2048] = A[M,K](bf16) @ W[2048,K]^T(bf16) + (ba+bb) ----------------
template <typename XGT>
__global__ __launch_bounds__(256, 1) void k_gemm_bias(
    const unsigned short* __restrict__ A, const unsigned short* __restrict__ Bw,
    const float* __restrict__ ba, const float* __restrict__ bb,
    XGT* __restrict__ C, int K, int ntn) {
  __shared__ unsigned short lds[16384];
  const int bid = blockIdx.x;
  const int nt = bid % ntn, mt = bid / ntn;
  const int tid = threadIdx.x;
  const int lane = tid & 63, wv = tid >> 6;
  const int wm = wv & 1, wn = wv >> 1;
  f32x4 acc[4][4] = {};
  const int nkt = K >> 6;
  const size_t ar0 = (size_t)mt * 128, br0 = (size_t)nt * 128;
  for (int kt = 0; kt < nkt; ++kt) {
    __syncthreads();
#pragma unroll
    for (int jj = 0; jj < 4; ++jj) {
      int g = tid + jj * 256;
      int row = g >> 3, gc = g & 7;
      int dst = (((row >> 4) * 2 + (gc >> 2)) * 64 + ((row & 15) + ((gc & 3) << 4))) * 8;
      uint4 va = *(const uint4*)(A + (ar0 + row) * (size_t)K + (size_t)kt * 64 + gc * 8);
      *(uint4*)&lds[dst] = va;
      uint4 vb = *(const uint4*)(Bw + (br0 + row) * (size_t)K + (size_t)kt * 64 + gc * 8);
      *(uint4*)&lds[8192 + dst] = vb;
    }
    __syncthreads();
#pragma unroll
    for (int kk = 0; kk < 2; ++kk) {
      short8 af[4], bf[4];
#pragma unroll
      for (int m = 0; m < 4; ++m)
        af[m] = *(const short8*)&lds[(((wm * 4 + m) * 2 + kk) * 64 + lane) * 8];
#pragma unroll
      for (int n = 0; n < 4; ++n)
        bf[n] = *(const short8*)&lds[8192 + (((wn * 4 + n) * 2 + kk) * 64 + lane) * 8];
#pragma unroll
      for (int m = 0; m < 4; ++m)
#pragma unroll
        for (int n = 0; n < 4; ++n)
          acc[m][n] = __builtin_amdgcn_mfma_f32_16x16x32_bf16(af[m], bf[n], acc[m][n], 0, 0, 0);
    }
  }
#pragma unroll
  for (int n = 0; n < 4; ++n) {
    int col = (int)br0 + wn * 64 + n * 16 + (lane & 15);
    float bsum = ba[col] + bb[col];
#pragma unroll
    for (int m = 0; m < 4; ++m) {
      size_t row = ar0 + wm * 64 + m * 16 + ((lane >> 4) * 4);
#pragma unroll
      for (int r = 0; r < 4; ++r)
        stc(C + (row + r) * G4 + col, acc[m][n][r] + bsum);
    }
  }
}

// ---------------- fused 2-layer persistent LSTM (v4) ----------------
// 128 WGs x 4 waves. WGs 0..63 = layer 0 (consume precomputed xg0), WGs 64..127 =
// layer 1 (compute input gates on the fly from h0(t) with W_ih1). WG (cg,bh):
// h-cols [cg*16,+16), batches [bh*32,+32). Wave s computes gate section s.
// h exchanged via LLC relaxed atomics (fence-free, see v3). Layer-1 tick t runs
// one tick behind layer-0 -> total serial span ~ T+1 ticks instead of 2T.
template <typename XGT>
__global__ __launch_bounds__(256, 1) void k_lstm_fused(
    const XGT* __restrict__ xg0,         // [T,B,4H] layer-0 input gates
    const float* __restrict__ whh0,      // [4H,H]
    const float* __restrict__ wih1,      // [4H,H]
    const float* __restrict__ whh1,      // [4H,H]
    const float* __restrict__ bih1, const float* __restrict__ bhh1,
    unsigned short* __restrict__ h0,     // [T,B,H]
    unsigned short* __restrict__ h1,     // [T,B,H]
    int* __restrict__ flags0, int* __restrict__ flags1) {
  // hbuf layout: granule g=0..63 (16B col-chunk), row b=0..31, XOR-swizzled:
  // elem = g*256 + (b ^ (g&7))*8  -> <=2-way bank conflicts on stage-write & frag-read
  __shared__ unsigned short hbufA[32 * 512];   // 32KB
  __shared__ unsigned short hbufB[32 * 512];   // 32KB (layer 1 only)
  __shared__ float gbuf[8 * 64 * 5];           // 10KB gate exchange
  __shared__ unsigned short hstage[32 * 20];   // padded row stride 20
  const int wgid = blockIdx.x;
  const int wg2 = wgid & 63;
  const int cg = wg2 >> 1, bh = wg2 & 1;
  const int tid = threadIdx.x;
  const int lane = tid & 63, wv = tid >> 6;
  const int l15 = lane & 15, l4 = lane >> 4;
  const int um = wv >> 1, rb = (wv & 1) * 2;
  const int fidx = ((lane & 31) * 2 + bh) * 32;

  if (wgid < 64) {
    // ================= LAYER 0 =================
    short8 wreg[16];
    {
      const float* wrow = whh0 + ((size_t)wv * H_ + cg * 16 + l15) * H_ + l4 * 8;
#pragma unroll
      for (int kk = 0; kk < 16; ++kk) {
        float4 v0 = *(const float4*)(wrow + kk * 32);
        float4 v1 = *(const float4*)(wrow + kk * 32 + 4);
        unsigned short o[8] = { f2bf(v0.x), f2bf(v0.y), f2bf(v0.z), f2bf(v0.w),
                                f2bf(v1.x), f2bf(v1.y), f2bf(v1.z), f2bf(v1.w) };
        wreg[kk] = *(const short8*)o;
      }
    }
    float c2[2] = {0.f, 0.f};

    for (int t = 0; t < T_; ++t) {
      float xr[2][4];
      {
        const XGT* xb = xg0 + ((size_t)t * B_ + bh * 32 + um * 16 + l4 * 4 + rb) * (size_t)G4 + cg * 16 + l15;
#pragma unroll
        for (int rr = 0; rr < 2; ++rr)
#pragma unroll
          for (int s = 0; s < 4; ++s)
            xr[rr][s] = ldx(xb + (size_t)rr * G4 + s * H_);
      }
      if (t > 0) {
        for (;;) {
          int v = (lane < 32) ? cohload_i32(flags0 + fidx) : 0x7fffffff;
          if (__all(v >= t)) break;
          __builtin_amdgcn_s_sleep(1);
        }
        __builtin_amdgcn_sched_barrier(0);
        asm volatile("" ::: "memory");
        const char* hp = (const char*)(h0 + ((size_t)(t - 1) * B_ + bh * 32) * H_);
        unsigned long long tmp[16];
#pragma unroll
        for (int j = 0; j < 8; ++j) {
          int ch = tid + j * 256;
          tmp[2 * j]     = cohload_u64(hp + (size_t)ch * 16);
          tmp[2 * j + 1] = cohload_u64(hp + (size_t)ch * 16 + 8);
        }
#pragma unroll
        for (int j = 0; j < 8; ++j) {
          int ch = tid + j * 256;
          int b = ch >> 6, g = ch & 63;
          union { unsigned long long q[2]; uint4 v; } u;
          u.q[0] = tmp[2 * j]; u.q[1] = tmp[2 * j + 1];
          *(uint4*)&hbufA[g * 256 + (b ^ (g & 7)) * 8] = u.v;
        }
      }
      __syncthreads();

      f32x4 acc[2];
      {
        f32x4 aE[2] = {}, aO[2] = {};
        if (t > 0) {
#pragma unroll
          for (int kk = 0; kk < 16; kk += 2) {
            int g0 = kk * 4 + l4, g1 = (kk + 1) * 4 + l4;
            int e0 = g0 * 256 + (l15 ^ (g0 & 7)) * 8;
            int e1 = g1 * 256 + (l15 ^ (g1 & 7)) * 8;
            short8 x0 = *(const short8*)&hbufA[e0];
            short8 x1 = *(const short8*)&hbufA[e0 + 128];
            short8 y0 = *(const short8*)&hbufA[e1];
            short8 y1 = *(const short8*)&hbufA[e1 + 128];
            aE[0] = __builtin_amdgcn_mfma_f32_16x16x32_bf16(x0, wreg[kk], aE[0], 0, 0, 0);
            aE[1] = __builtin_amdgcn_mfma_f32_16x16x32_bf16(x1, wreg[kk], aE[1], 0, 0, 0);
            aO[0] = __builtin_amdgcn_mfma_f32_16x16x32_bf16(y0, wreg[kk + 1], aO[0], 0, 0, 0);
            aO[1] = __builtin_amdgcn_mfma_f32_16x16x32_bf16(y1, wreg[kk + 1], aO[1], 0, 0, 0);
          }
        }
        acc[0] = aE[0] + aO[0];
        acc[1] = aE[1] + aO[1];
      }

#pragma unroll
      for (int m = 0; m < 2; ++m)
#pragma unroll
        for (int r = 0; r < 4; ++r)
          gbuf[((wv * 2 + m) * 64 + lane) * 5 + r] = acc[m][r];
      __syncthreads();

#pragma unroll
      for (int rr = 0; rr < 2; ++rr) {
        int r = rb + rr;
        float g4v[4];
#pragma unroll
        for (int s = 0; s < 4; ++s)
          g4v[s] = gbuf[((s * 2 + um) * 64 + lane) * 5 + r] + xr[rr][s];
        float iv = sigmoidf_(g4v[0]);
        float fv = sigmoidf_(g4v[1]);
        float gv = tanhf_(g4v[2]);
        float ov = sigmoidf_(g4v[3]);
        float cn = fv * c2[rr] + iv * gv;
        c2[rr] = cn;
        hstage[(um * 16 + l4 * 4 + r) * 20 + l15] = f2bf(ov * tanhf_(cn));
      }
      __syncthreads();

      if (tid < 128) {
        int bl = tid >> 2, q = tid & 3;
        unsigned long long v = *(const unsigned long long*)&hstage[bl * 20 + q * 4];
        cohstore_u64(h0 + ((size_t)t * B_ + bh * 32 + bl) * H_ + cg * 16 + q * 4, v);
      }
      asm volatile("s_waitcnt vmcnt(0)" ::: "memory");
      __syncthreads();
      if (tid == 0) cohstore_i32(flags0 + wg2 * 32, t + 1);
    }
  } else {
    // ================= LAYER 1 =================
    short8 wregA[16], wregB[16];
    {
      const float* wrA = wih1 + ((size_t)wv * H_ + cg * 16 + l15) * H_ + l4 * 8;
      const float* wrB = whh1 + ((size_t)wv * H_ + cg * 16 + l15) * H_ + l4 * 8;
#pragma unroll
      for (int kk = 0; kk < 16; ++kk) {
        float4 a0 = *(const float4*)(wrA + kk * 32);
        float4 a1 = *(const float4*)(wrA + kk * 32 + 4);
        unsigned short oa[8] = { f2bf(a0.x), f2bf(a0.y), f2bf(a0.z), f2bf(a0.w),
                                 f2bf(a1.x), f2bf(a1.y), f2bf(a1.z), f2bf(a1.w) };
        wregA[kk] = *(const short8*)oa;
        float4 b0 = *(const float4*)(wrB + kk * 32);
        float4 b1 = *(const float4*)(wrB + kk * 32 + 4);
        unsigned short ob[8] = { f2bf(b0.x), f2bf(b0.y), f2bf(b0.z), f2bf(b0.w),
                                 f2bf(b1.x), f2bf(b1.y), f2bf(b1.z), f2bf(b1.w) };
        wregB[kk] = *(const short8*)ob;
      }
    }
    float b1s[4];
    {
      int col = cg * 16 + l15;
#pragma unroll
      for (int s = 0; s < 4; ++s) b1s[s] = bih1[s * H_ + col] + bhh1[s * H_ + col];
    }
    float c2[2] = {0.f, 0.f};

    for (int t = 0; t < T_; ++t) {
      {
        const int need = (lane < 32) ? (t + 1) : t;
        const int* fp = (lane < 32) ? flags0 : flags1;
        for (;;) {
          int v = cohload_i32(fp + fidx);
          if (__all(v >= need)) break;
          __builtin_amdgcn_s_sleep(1);
        }
        __builtin_amdgcn_sched_barrier(0);
        asm volatile("" ::: "memory");
        // stage h0(t) -> hbufA, and h1(t-1) -> hbufB
        const char* hpA = (const char*)(h0 + ((size_t)t * B_ + bh * 32) * H_);
        const char* hpB = (const char*)(h1 + ((size_t)(t - 1) * B_ + bh * 32) * H_);
        unsigned long long ta[16], tb[16];
#pragma unroll
        for (int j = 0; j < 8; ++j) {
          int ch = tid + j * 256;
          ta[2 * j]     = cohload_u64(hpA + (size_t)ch * 16);
          ta[2 * j + 1] = cohload_u64(hpA + (size_t)ch * 16 + 8);
        }
        if (t > 0) {
#pragma unroll
          for (int j = 0; j < 8; ++j) {
            int ch = tid + j * 256;
            tb[2 * j]     = cohload_u64(hpB + (size_t)ch * 16);
            tb[2 * j + 1] = cohload_u64(hpB + (size_t)ch * 16 + 8);
          }
        }
#pragma unroll
        for (int j = 0; j < 8; ++j) {
          int ch = tid + j * 256;
          int b = ch >> 6, g = ch & 63;
          int de = g * 256 + (b ^ (g & 7)) * 8;
          union { unsigned long long q[2]; uint4 v; } u;
          u.q[0] = ta[2 * j]; u.q[1] = ta[2 * j + 1];
          *(uint4*)&hbufA[de] = u.v;
          if (t > 0) {
            u.q[0] = tb[2 * j]; u.q[1] = tb[2 * j + 1];
            *(uint4*)&hbufB[de] = u.v;
          }
        }
      }
      __syncthreads();

      f32x4 acc[2];
      {
        f32x4 aA[2] = {}, aB[2] = {};
#pragma unroll
        for (int kk = 0; kk < 16; ++kk) {
          int g = kk * 4 + l4;
          int e = g * 256 + (l15 ^ (g & 7)) * 8;
          short8 a0 = *(const short8*)&hbufA[e];
          short8 a1 = *(const short8*)&hbufA[e + 128];
          aA[0] = __builtin_amdgcn_mfma_f32_16x16x32_bf16(a0, wregA[kk], aA[0], 0, 0, 0);
          aA[1] = __builtin_amdgcn_mfma_f32_16x16x32_bf16(a1, wregA[kk], aA[1], 0, 0, 0);
          if (t > 0) {
            short8 b0 = *(const short8*)&hbufB[e];
            short8 b1v = *(const short8*)&hbufB[e + 128];
            aB[0] = __builtin_amdgcn_mfma_f32_16x16x32_bf16(b0, wregB[kk], aB[0], 0, 0, 0);
            aB[1] = __builtin_amdgcn_mfma_f32_16x16x32_bf16(b1v, wregB[kk], aB[1], 0, 0, 0);
          }
        }
        acc[0] = aA[0] + aB[0];
        acc[1] = aA[1] + aB[1];
      }

#pragma unroll
      for (int m = 0; m < 2; ++m)
#pragma unroll
        for (int r = 0; r < 4; ++r)
          gbuf[((wv * 2 + m) * 64 + lane) * 5 + r] = acc[m][r];
      __syncthreads();

#pragma unroll
      for (int rr = 0; rr < 2; ++rr) {
        int r = rb + rr;
        float g4v[4];
#pragma unroll
        for (int s = 0; s < 4; ++s)
          g4v[s] = gbuf[((s * 2 + um) * 64 + lane) * 5 + r] + b1s[s];
        float iv = sigmoidf_(g4v[0]);
        float fv = sigmoidf_(g4v[1]);
        float gv = tanhf_(g4v[2]);
        float ov = sigmoidf_(g4v[3]);
        float cn = fv * c2[rr] + iv * gv;
        c2[rr] = cn;
        hstage[(um * 16 + l4 * 4 + r) * 20 + l15] = f2bf(ov * tanhf_(cn));
      }
      __syncthreads();

      if (tid < 128) {
        int bl = tid >> 2, q = tid & 3;
        unsigned long long v = *(const unsigned long long*)&hstage[bl * 20 + q * 4];
        cohstore_u64(h1 + ((size_t)t * B_ + bh * 32 + bl) * H_ + cg * 16 + q * 4, v);
      }
      asm volatile("s_waitcnt vmcnt(0)" ::: "memory");
      __syncthreads();
      if (tid == 0) cohstore_i32(flags1 + wg2 * 32, t + 1);
    }
  }
}

// ---------------- final FC + sigmoid ----------------
__global__ void k_fc(const unsigned short* __restrict__ h, const float* __restrict__ w,
                     const float* __restrict__ bfc, float* __restrict__ out) {
  int b = threadIdx.x;
  if (b < B_) {
    const unsigned short* hb = h + (size_t)b * H_;
    float s = 0.f;
    for (int j = 0; j < H_; ++j) s += bf2f(hb[j]) * w[j];
    out[b] = sigmoidf_(s + bfc[0]);
  }
}

extern "C" void kernel_launch(void* const* d_in, const int* in_sizes, int n_in,
                              void* d_out, int out_size, void* d_ws, size_t ws_size,
                              hipStream_t stream) {
  (void)in_sizes; (void)n_in; (void)out_size;
  const float* x    = (const float*)d_in[0];
  const float* wih0 = (const float*)d_in[1];
  const float* whh0 = (const float*)d_in[2];
  const float* bih0 = (const float*)d_in[3];
  const float* bhh0 = (const float*)d_in[4];
  const float* wih1 = (const float*)d_in[5];
  const float* whh1 = (const float*)d_in[6];
  const float* bih1 = (const float*)d_in[7];
  const float* bhh1 = (const float*)d_in[8];
  const float* wfc  = (const float*)d_in[9];
  const float* bfc  = (const float*)d_in[10];
  float* out = (float*)d_out;

  char* ws = (char*)d_ws;
  int* flags0 = (int*)ws;                   // 64 x 32 ints = 8KB
  int* flags1 = (int*)(ws + 8192);          // 8KB
  size_t off = 16384;
  unsigned short* xT = (unsigned short*)(ws + off);    off += (size_t)T_ * B_ * DIN * 2;
  unsigned short* wih0b = (unsigned short*)(ws + off); off += (size_t)G4 * DIN * 2;
  unsigned short* h0 = (unsigned short*)(ws + off);    off += (size_t)T_ * B_ * H_ * 2;
  unsigned short* h1 = (unsigned short*)(ws + off);    off += (size_t)T_ * B_ * H_ * 2;
  size_t xg_off = off;
  const size_t need_f32 = xg_off + (size_t)T_ * B_ * G4 * 4;

  const int gemm_grid = (T_ * B_ / 128) * (G4 / 128);
  const int ntn = G4 / 128;

  hipMemsetAsync(flags0, 0, 16384, stream);
  k_convert_x<<<2048, 256, 0, stream>>>(x, xT);
  k_convert_w<<<512, 256, 0, stream>>>(wih0, wih0b, G4 * DIN);

  if (ws_size >= need_f32) {
    float* xgbuf = (float*)(ws + xg_off);
    k_gemm_bias<float><<<gemm_grid, 256, 0, stream>>>(xT, wih0b, bih0, bhh0, xgbuf, DIN, ntn);
    k_lstm_fused<float><<<NWGF, 256, 0, stream>>>(xgbuf, whh0, wih1, whh1, bih1, bhh1,
                                                  h0, h1, flags0, flags1);
  } else {
    unsigned short* xgbuf = (unsigned short*)(ws + xg_off);
    k_gemm_bias<unsigned short><<<gemm_grid, 256, 0, stream>>>(xT, wih0b, bih0, bhh0, xgbuf, DIN, ntn);
    k_lstm_fused<unsigned short><<<NWGF, 256, 0, stream>>>(xgbuf, whh0, wih1, whh1, bih1, bhh1,
                                                           h0, h1, flags0, flags1);
  }
  k_fc<<<1, 64, 0, stream>>>(h1 + (size_t)(T_ - 1) * B_ * H_, wfc, bfc, out);
}